// Round 2
// baseline (2370.105 us; speedup 1.0000x reference)
//
#include <hip/hip_runtime.h>

typedef unsigned int u32;
typedef unsigned long long u64;
typedef float f4 __attribute__((ext_vector_type(4)));

// ctrl u32 offsets
#define C_PT    0    // pre-threshold coarse bin
#define C_NC    16   // candidate count (atomic, block-granular)
#define C_T     32   // exact 31-bit threshold
#define C_CUT   33   // tie index cutoff
#define C_NM    48   // member count (atomic, block-granular)

#define MAIN_R      16            // float4 per thread in k_main
#define MAIN_ELEMS  (256u * MAIN_R)
#define PATCH_CHUNK 2048u
#define RCHUNK      4096          // keys staged per rank block

__device__ __forceinline__ u32 fkey32(u32 fb) {
  return (fb & 0x80000000u) ? ~fb : (fb | 0x80000000u);
}

// ---------------- Sampled coarse histogram (1/32 of data) ----------
__global__ void __launch_bounds__(256) k_sample(const float4* __restrict__ g,
                                                const float4* __restrict__ r,
                                                u32* __restrict__ shist, int n4) {
  __shared__ u32 lh[2048];
  for (int i = threadIdx.x; i < 2048; i += 256) lh[i] = 0;
  __syncthreads();
  u32 base = blockIdx.x * 32768u;
#pragma unroll
  for (int j = 0; j < 4; j++) {
    u32 i = base + threadIdx.x + (u32)j * 256u;
    if ((int)i < n4) {
      float4 a = g[i]; float4 b = r[i];
      atomicAdd(&lh[(__float_as_uint(a.x + b.x) & 0x7fffffffu) >> 20], 1u);
      atomicAdd(&lh[(__float_as_uint(a.y + b.y) & 0x7fffffffu) >> 20], 1u);
      atomicAdd(&lh[(__float_as_uint(a.z + b.z) & 0x7fffffffu) >> 20], 1u);
      atomicAdd(&lh[(__float_as_uint(a.w + b.w) & 0x7fffffffu) >> 20], 1u);
    }
  }
  __syncthreads();
  for (int i = threadIdx.x; i < 2048; i += 256)
    if (lh[i]) atomicAdd(&shist[i], lh[i]);
}

// ---------------- Pick conservative pre-threshold bin ----------
__global__ void __launch_bounds__(1024) k_pick(const u32* __restrict__ shist,
                                               u32* __restrict__ ctrl, u32 target) {
  __shared__ u32 b0[2048], b1[2048];
  u32 t = threadIdx.x;
  b0[t] = shist[t]; b0[t + 1024] = shist[t + 1024];
  __syncthreads();
  u32* src = b0; u32* dst = b1;
  for (u32 off = 1; off < 2048; off <<= 1) {
    for (u32 i = t; i < 2048; i += 1024) {
      u32 v = src[i];
      if (i + off < 2048) v += src[i + off];
      dst[i] = v;
    }
    __syncthreads();
    u32* tmp = src; src = dst; dst = tmp;
  }
  for (u32 i = t; i < 2048; i += 1024) {
    u32 cum = src[i];
    u32 nxt = (i + 1 < 2048) ? src[i + 1] : 0u;
    if (cum >= target && nxt < target) ctrl[C_PT] = i;
  }
}

// ---------------- Big pass: stream res + candidate compaction + exact coarse hist -----
__global__ void __launch_bounds__(256) k_main(const f4* __restrict__ g,
                                              const f4* __restrict__ r,
                                              const float* __restrict__ momp,
                                              f4* __restrict__ res4,
                                              u32* __restrict__ ctrl,
                                              u64* __restrict__ cand, u32 cap, int n4,
                                              u32* __restrict__ hist2) {
  __shared__ u64 st[2048];
  __shared__ u32 lcnt, lbase;
  if (threadIdx.x == 0) lcnt = 0;
  __syncthreads();
  float m = momp[0];
  u32 PT = ctrl[C_PT];
  u32 seg = blockIdx.x * MAIN_ELEMS;
#pragma unroll 4
  for (int j = 0; j < MAIN_R; j++) {
    u32 i = seg + (u32)j * 256u + threadIdx.x;
    if ((int)i < n4) {
      f4 a = __builtin_nontemporal_load(&g[i]);
      f4 b = __builtin_nontemporal_load(&r[i]);
      f4 ro;
      ro.x = b.x + m * a.x; ro.y = b.y + m * a.y;
      ro.z = b.z + m * a.z; ro.w = b.w + m * a.w;
      __builtin_nontemporal_store(ro, &res4[i]);
      u32 base4 = i * 4u;
      float c0 = a.x + b.x, c1 = a.y + b.y, c2 = a.z + b.z, c3 = a.w + b.w;
#define PUSH(CV, J) { u32 cb = __float_as_uint(CV); u32 u = cb & 0x7fffffffu; \
      if ((u >> 20) >= PT) { \
        u64 e = ((u64)u << 32) | (u64)((base4 + J) | (cb & 0x80000000u)); \
        u32 p = atomicAdd(&lcnt, 1u); \
        if (p < 2048u) st[p] = e; \
        else { u32 gs = atomicAdd(&ctrl[C_NC], 1u); \
               if (gs < cap) { cand[gs] = e; atomicAdd(&hist2[u >> 20], 1u); } } } }
      PUSH(c0, 0u)
      PUSH(c1, 1u)
      PUSH(c2, 2u)
      PUSH(c3, 3u)
#undef PUSH
    }
  }
  __syncthreads();
  u32 cnt = lcnt; if (cnt > 2048u) cnt = 2048u;
  if (threadIdx.x == 0) lbase = atomicAdd(&ctrl[C_NC], cnt);
  __syncthreads();
  u32 lb = lbase;
  for (u32 p = threadIdx.x; p < cnt; p += 256u) {
    u32 s = lb + p;
    if (s < cap) {
      u64 e = st[p];
      cand[s] = e;
      atomicAdd(&hist2[(u32)(e >> 52)], 1u);
    }
  }
}

// ---------------- Exact 31-bit select over candidates (single block) ----------
// Level 0 comes free from hist2 (built in k_main). One full candidate scan does
// level-1 histogram AND compacts boundary-bin entries to candB; levels 2 + tie
// then only touch the compacted subset.
__global__ void __launch_bounds__(1024) k_refine(u32* __restrict__ ctrl,
                                                 const u64* __restrict__ cand,
                                                 u32 cap, u32 K,
                                                 const u32* __restrict__ hist2,
                                                 u64* __restrict__ candB) {
  __shared__ u32 h[2048], h2[2048];
  __shared__ u32 res[8];
  __shared__ u32 tie[2048];
  __shared__ u32 nt, nb;
  u32 t = threadIdx.x;
  u32 lane = t & 63u;
  u32 nc = ctrl[C_NC]; if (nc > cap) nc = cap;

  // level 0: suffix-sum of precomputed exact coarse histogram
  h[t] = hist2[t]; h[t + 1024] = hist2[t + 1024];
  if (t == 0) { nt = 0; nb = 0; }
  __syncthreads();
  u32* src = h; u32* dst = h2;
  for (u32 off = 1; off < 2048; off <<= 1) {
    for (u32 i = t; i < 2048; i += 1024) {
      u32 v = src[i];
      if (i + off < 2048) v += src[i + off];
      dst[i] = v;
    }
    __syncthreads();
    u32* tmp = src; src = dst; dst = tmp;
  }
  for (u32 i = t; i < 2048; i += 1024) {
    u32 cum = src[i];
    u32 nxt = (i + 1 < 2048) ? src[i + 1] : 0u;
    if (cum >= K && nxt < K) { res[0] = i; res[1] = nxt; }
  }
  __syncthreads();
  u32 B0 = res[0];
  u32 r0 = K - res[1];
  __syncthreads();

  // level 1: single full scan — hist of bits 19..10 for bin==B0, plus compaction
  h[t] = 0;
  __syncthreads();
  for (u32 i = t; i < nc; i += 1024) {
    u64 e = cand[i];
    u32 u = (u32)(e >> 32);
    bool pred = ((u >> 20) == B0);
    if (pred) atomicAdd(&h[(u >> 10) & 1023u], 1u);
    // wave-aggregated compaction append
    u64 mask = __ballot(pred);
    if (mask) {
      u32 pre = (u32)__popcll(mask & ((1ull << lane) - 1ull));
      u32 cntw = (u32)__popcll(mask);
      u32 leader = (u32)__ffsll((unsigned long long)mask) - 1u;
      u32 base = 0;
      if (lane == leader) base = atomicAdd(&nb, cntw);
      base = (u32)__shfl((int)base, (int)leader, 64);
      if (pred) candB[base + pre] = e;
    }
  }
  __syncthreads();
  u32 cntB = nb;
  src = h; dst = h2;
  for (u32 off = 1; off < 1024; off <<= 1) {
    u32 v = src[t];
    if (t + off < 1024) v += src[t + off];
    dst[t] = v;
    __syncthreads();
    u32* tmp = src; src = dst; dst = tmp;
  }
  {
    u32 cum = src[t];
    u32 nxt = (t + 1 < 1024) ? src[t + 1] : 0u;
    if (cum >= r0 && nxt < r0) { res[2] = t; res[3] = nxt; }
  }
  __syncthreads();
  u32 B1 = res[2];
  u32 r1 = r0 - res[3];
  u32 hi21 = (B0 << 10) | B1;
  __syncthreads();

  // level 2: bits 9..0, scanning only the compacted boundary-bin subset
  h[t] = 0;
  __syncthreads();
  for (u32 i = t; i < cntB; i += 1024) {
    u32 u = (u32)(candB[i] >> 32);
    if ((u >> 10) == hi21) atomicAdd(&h[u & 1023u], 1u);
  }
  __syncthreads();
  src = h; dst = h2;
  for (u32 off = 1; off < 1024; off <<= 1) {
    u32 v = src[t];
    if (t + off < 1024) v += src[t + off];
    dst[t] = v;
    __syncthreads();
    u32* tmp = src; src = dst; dst = tmp;
  }
  {
    u32 cum = src[t];
    u32 nxt = (t + 1 < 1024) ? src[t + 1] : 0u;
    if (cum >= r1 && nxt < r1) { res[4] = t; res[5] = nxt; }
  }
  __syncthreads();
  u32 B2 = res[4];
  u32 r2 = r1 - res[5];
  u32 T = (hi21 << 10) | B2;
  __syncthreads();

  // tie resolution over compacted subset: r2-th smallest index among u == T
  for (u32 i = t; i < cntB; i += 1024) {
    u64 e = candB[i];
    if ((u32)(e >> 32) == T) {
      u32 p = atomicAdd(&nt, 1u);
      if (p < 2048u) tie[p] = (u32)e & 0x7fffffffu;
    }
  }
  __syncthreads();
  u32 ntc = nt; if (ntc > 2048u) ntc = 2048u;
  for (u32 i = t; i < ntc; i += 1024) {
    u32 ti = tie[i];
    u32 rank = 0;
    for (u32 j = 0; j < ntc; j++) rank += (tie[j] < ti) ? 1u : 0u;
    if (rank == r2 - 1u) ctrl[C_CUT] = ti;
  }
  if (t == 0) ctrl[C_T] = T;
}

// ---------------- Patch chosen candidates (block-aggregated member append) --------
__global__ void __launch_bounds__(256) k_patch(u32* __restrict__ ctrl,
                                               const u64* __restrict__ cand, u32 cap,
                                               float* __restrict__ res_out,
                                               float* __restrict__ sp_out,
                                               u64* __restrict__ memb) {
  __shared__ u64 st[PATCH_CHUNK];
  __shared__ u32 cnt, basep;
  u32 b0 = blockIdx.x * PATCH_CHUNK;
  u32 nc = ctrl[C_NC]; if (nc > cap) nc = cap;
  if (b0 >= nc) return;                    // uniform early-out, before any sync
  if (threadIdx.x == 0) cnt = 0;
  __syncthreads();
  u32 T = ctrl[C_T];
  u32 cut = ctrl[C_CUT];
  for (u32 j = threadIdx.x; j < PATCH_CHUNK; j += 256u) {
    u32 i = b0 + j;
    if (i < nc) {
      u64 e = cand[i];
      u32 u = (u32)(e >> 32);
      u32 low = (u32)e;
      u32 idx = low & 0x7fffffffu;
      bool chosen = (u > T) || (u == T && idx <= cut);
      if (chosen) {
        u32 cb = u | (low & 0x80000000u);
        res_out[idx] = 0.f;
        sp_out[idx] = __uint_as_float(cb);
        u32 p = atomicAdd(&cnt, 1u);
        st[p] = ((u64)fkey32(cb) << 32) | (u64)idx;
      }
    }
  }
  __syncthreads();
  if (threadIdx.x == 0) basep = atomicAdd(&ctrl[C_NM], cnt);
  __syncthreads();
  u32 bp = basep;
  for (u32 p = threadIdx.x; p < cnt; p += 256u)
    memb[bp + p] = st[p];
}

// ---------------- Rank pass: partial[ct][m] = #{j in chunk ct : key_j < key_m} -----
__global__ void __launch_bounds__(256) k_rank(const u64* __restrict__ memb,
                                              u32* __restrict__ partial,
                                              int k, int mpad) {
  __shared__ u64 s[RCHUNK];
  u32 cbase = blockIdx.y * RCHUNK;
  for (u32 j = threadIdx.x; j < RCHUNK; j += 256u) {
    u32 jj = cbase + j;
    s[j] = (jj < (u32)k) ? memb[jj] : ~0ull;
  }
  __syncthreads();
  u32 m0 = blockIdx.x * 1024u + threadIdx.x * 4u;
  u64 k0 = (m0 + 0 < (u32)k) ? memb[m0 + 0] : 0ull;
  u64 k1 = (m0 + 1 < (u32)k) ? memb[m0 + 1] : 0ull;
  u64 k2 = (m0 + 2 < (u32)k) ? memb[m0 + 2] : 0ull;
  u64 k3 = (m0 + 3 < (u32)k) ? memb[m0 + 3] : 0ull;
  u32 r0 = 0, r1 = 0, r2 = 0, r3 = 0;
  const ulonglong2* s2 = (const ulonglong2*)s;
#pragma unroll 4
  for (int j = 0; j < RCHUNK / 2; j++) {
    ulonglong2 kk = s2[j];
    r0 += (kk.x < k0) + (kk.y < k0);
    r1 += (kk.x < k1) + (kk.y < k1);
    r2 += (kk.x < k2) + (kk.y < k2);
    r3 += (kk.x < k3) + (kk.y < k3);
  }
  u32* row = partial + (size_t)blockIdx.y * (u32)mpad;
  if (m0 + 3 < (u32)k) {
    uint4 v; v.x = r0; v.y = r1; v.z = r2; v.w = r3;
    *(uint4*)(row + m0) = v;
  } else {
    if (m0 + 0 < (u32)k) row[m0 + 0] = r0;
    if (m0 + 1 < (u32)k) row[m0 + 1] = r1;
    if (m0 + 2 < (u32)k) row[m0 + 2] = r2;
    if (m0 + 3 < (u32)k) row[m0 + 3] = r3;
  }
}

// ---------------- Reduce partial ranks + emit outputs ----------
__global__ void __launch_bounds__(256) k_out(const u64* __restrict__ memb,
                                             const u32* __restrict__ partial,
                                             float* __restrict__ out,
                                             int k, int mpad, int ct) {
  int m = blockIdx.x * 256 + (int)threadIdx.x;
  if (m >= k) return;
  u32 rank = 0;
  for (int c = 0; c < ct; c++)
    rank += partial[(size_t)c * (u32)mpad + (u32)m];
  u64 e = memb[m];
  u32 idx = (u32)e & 0x7fffffffu;
  u32 h = (u32)(e >> 32);
  u32 fb = (h & 0x80000000u) ? (h ^ 0x80000000u) : ~h;
  out[rank] = (float)idx;
  out[k + rank] = __uint_as_float(fb);
}

extern "C" void kernel_launch(void* const* d_in, const int* in_sizes, int n_in,
                              void* d_out, int out_size, void* d_ws, size_t ws_size,
                              hipStream_t stream) {
  const float* g   = (const float*)d_in[0];
  const float* r   = (const float*)d_in[1];
  const float* mom = (const float*)d_in[2];
  int n = in_sizes[0];
  int k = (out_size - 2 * n) / 2;
  int n4 = n / 4;

  float* out = (float*)d_out;
  float* res_out = out + 2 * (size_t)k;
  float* sp_out  = res_out + (size_t)n;

  unsigned char* ws = (unsigned char*)d_ws;
  u32* ctrl    = (u32*)ws;                    // [0, 256)
  u32* shist   = (u32*)(ws + 1024);           // [1024, 9216)
  u32* hist2   = (u32*)(ws + 9216);           // [9216, 17408) exact coarse hist
  u64* memb    = (u64*)(ws + 32768);          // ~1 MB member list
  u32* partial = (u32*)(ws + 1048576);        // up to 8 MB partial ranks
  u64* candB   = (u64*)(ws + 1048576);        // aliases partial (dead until k_rank)
  size_t cand_off = 9437184;                  // 9 MB
  u64* cand    = (u64*)(ws + cand_off);

  u32 cap = 524288u;
  if (ws_size < cand_off + (size_t)cap * 8)
    cap = (u32)((ws_size - cand_off) / 8);

  // sample target: expected full-data candidate count ~ 3*k (clamped)
  int nsc = n4 / 32768; if (nsc < 1) nsc = 1;
  double sampleN = (double)nsc * 1024.0 * 4.0;
  double want = 3.0 * (double)k;
  double capd = 0.5 * (double)cap;
  if (want > capd) want = capd;
  if (want < 1.5 * (double)k) want = 1.5 * (double)k;
  u32 target = (u32)(want * sampleN / (double)n) + 1u;

  int mtiles = (k + 1023) / 1024;
  int mpad   = mtiles * 1024;
  int ct     = (k + RCHUNK - 1) / RCHUNK;

  hipMemsetAsync(ws, 0, 32768, stream);                          // ctrl + shist + hist2
  hipMemsetAsync(sp_out, 0, (size_t)n * sizeof(float), stream);  // sparse zeros

  k_sample<<<nsc, 256, 0, stream>>>((const float4*)g, (const float4*)r, shist, n4);
  k_pick<<<1, 1024, 0, stream>>>(shist, ctrl, target);
  k_main<<<(n4 + (int)MAIN_ELEMS - 1) / (int)MAIN_ELEMS, 256, 0, stream>>>(
      (const f4*)g, (const f4*)r, mom, (f4*)res_out, ctrl, cand, cap, n4, hist2);
  k_refine<<<1, 1024, 0, stream>>>(ctrl, cand, cap, (u32)k, hist2, candB);
  k_patch<<<(int)((cap + PATCH_CHUNK - 1) / PATCH_CHUNK), 256, 0, stream>>>(
      ctrl, cand, cap, res_out, sp_out, memb);

  dim3 rg((u32)mtiles, (u32)ct);
  k_rank<<<rg, 256, 0, stream>>>(memb, partial, k, mpad);
  k_out<<<(k + 255) / 256, 256, 0, stream>>>(memb, partial, out, k, mpad, ct);
}

// Round 7
// 2321.781 us; speedup vs baseline: 1.0208x; 1.0208x over previous
//
#include <hip/hip_runtime.h>

typedef unsigned int u32;
typedef unsigned long long u64;
typedef float f4 __attribute__((ext_vector_type(4)));

// ctrl u32 offsets
#define C_PT    0    // pre-threshold coarse bin
#define C_NC    16   // candidate count (atomic, block-granular)
#define C_T     32   // exact 31-bit threshold
#define C_CUT   33   // tie index cutoff
#define C_NM    48   // member count (atomic, block-granular)

#define MAIN_R      16            // float4 per thread in k_main
#define MAIN_ELEMS  (256u * MAIN_R)
#define PATCH_CHUNK 2048u
#define RCHUNK      4096          // keys staged per rank block

__device__ __forceinline__ u32 fkey32(u32 fb) {
  return (fb & 0x80000000u) ? ~fb : (fb | 0x80000000u);
}

// ---------------- Sampled coarse histogram (1/32 of data) ----------
__global__ void __launch_bounds__(256) k_sample(const float4* __restrict__ g,
                                                const float4* __restrict__ r,
                                                u32* __restrict__ shist, int n4) {
  __shared__ u32 lh[2048];
  for (int i = threadIdx.x; i < 2048; i += 256) lh[i] = 0;
  __syncthreads();
  u32 base = blockIdx.x * 32768u;
#pragma unroll
  for (int j = 0; j < 4; j++) {
    u32 i = base + threadIdx.x + (u32)j * 256u;
    if ((int)i < n4) {
      float4 a = g[i]; float4 b = r[i];
      atomicAdd(&lh[(__float_as_uint(a.x + b.x) & 0x7fffffffu) >> 20], 1u);
      atomicAdd(&lh[(__float_as_uint(a.y + b.y) & 0x7fffffffu) >> 20], 1u);
      atomicAdd(&lh[(__float_as_uint(a.z + b.z) & 0x7fffffffu) >> 20], 1u);
      atomicAdd(&lh[(__float_as_uint(a.w + b.w) & 0x7fffffffu) >> 20], 1u);
    }
  }
  __syncthreads();
  for (int i = threadIdx.x; i < 2048; i += 256)
    if (lh[i]) atomicAdd(&shist[i], lh[i]);
}

// ---------------- Pick conservative pre-threshold bin ----------
__global__ void __launch_bounds__(1024) k_pick(const u32* __restrict__ shist,
                                               u32* __restrict__ ctrl, u32 target) {
  __shared__ u32 b0[2048], b1[2048];
  u32 t = threadIdx.x;
  b0[t] = shist[t]; b0[t + 1024] = shist[t + 1024];
  __syncthreads();
  u32* src = b0; u32* dst = b1;
  for (u32 off = 1; off < 2048; off <<= 1) {
    for (u32 i = t; i < 2048; i += 1024) {
      u32 v = src[i];
      if (i + off < 2048) v += src[i + off];
      dst[i] = v;
    }
    __syncthreads();
    u32* tmp = src; src = dst; dst = tmp;
  }
  for (u32 i = t; i < 2048; i += 1024) {
    u32 cum = src[i];
    u32 nxt = (i + 1 < 2048) ? src[i + 1] : 0u;
    if (cum >= target && nxt < target) ctrl[C_PT] = i;
  }
}

// ---------------- Big pass: stream res + zero sparse + candidates + exact hist -----
__global__ void __launch_bounds__(256) k_main(const f4* __restrict__ g,
                                              const f4* __restrict__ r,
                                              const float* __restrict__ momp,
                                              f4* __restrict__ res4,
                                              f4* __restrict__ sp4,
                                              u32* __restrict__ ctrl,
                                              u64* __restrict__ cand, u32 cap, int n4,
                                              u32* __restrict__ hist2) {
  __shared__ u64 st[2048];
  __shared__ u32 lcnt, lbase;
  if (threadIdx.x == 0) lcnt = 0;
  __syncthreads();
  float m = momp[0];
  u32 PT = ctrl[C_PT];
  u32 seg = blockIdx.x * MAIN_ELEMS;
  const f4 zz = {0.f, 0.f, 0.f, 0.f};

#define PUSH(CV, J, B4) { u32 cb = __float_as_uint(CV); u32 u = cb & 0x7fffffffu; \
  if ((u >> 20) >= PT) { \
    u64 e = ((u64)u << 32) | (u64)(((B4) + J) | (cb & 0x80000000u)); \
    u32 p = atomicAdd(&lcnt, 1u); \
    if (p < 2048u) st[p] = e; \
    else { u32 gs = atomicAdd(&ctrl[C_NC], 1u); \
           if (gs < cap) { cand[gs] = e; atomicAdd(&hist2[u >> 20], 1u); } } } }

#define PROC(II, A, B) { \
  f4 ro; ro.x = (B).x + m * (A).x; ro.y = (B).y + m * (A).y; \
  ro.z = (B).z + m * (A).z; ro.w = (B).w + m * (A).w; \
  res4[II] = ro; sp4[II] = zz; \
  u32 b4 = (II) * 4u; \
  float c0 = (A).x + (B).x, c1 = (A).y + (B).y, c2 = (A).z + (B).z, c3 = (A).w + (B).w; \
  PUSH(c0, 0u, b4) PUSH(c1, 1u, b4) PUSH(c2, 2u, b4) PUSH(c3, 3u, b4) }

  if (seg + MAIN_ELEMS <= (u32)n4) {
    // full block: batches of 4, 8 loads issued before any compute (ILP)
#pragma unroll
    for (int jb = 0; jb < MAIN_R / 4; jb++) {
      u32 i0 = seg + (u32)jb * 1024u + threadIdx.x;
      u32 i1 = i0 + 256u, i2 = i0 + 512u, i3 = i0 + 768u;
      f4 a0 = g[i0]; f4 a1 = g[i1]; f4 a2 = g[i2]; f4 a3 = g[i3];
      f4 b0 = r[i0]; f4 b1 = r[i1]; f4 b2 = r[i2]; f4 b3 = r[i3];
      PROC(i0, a0, b0)
      PROC(i1, a1, b1)
      PROC(i2, a2, b2)
      PROC(i3, a3, b3)
    }
  } else {
    for (int j = 0; j < MAIN_R; j++) {
      u32 i = seg + (u32)j * 256u + threadIdx.x;
      if ((int)i < n4) {
        f4 a = g[i]; f4 b = r[i];
        PROC(i, a, b)
      }
    }
  }
#undef PROC
#undef PUSH

  __syncthreads();
  u32 cnt = lcnt; if (cnt > 2048u) cnt = 2048u;
  if (threadIdx.x == 0) lbase = atomicAdd(&ctrl[C_NC], cnt);
  __syncthreads();
  u32 lb = lbase;
  for (u32 p = threadIdx.x; p < cnt; p += 256u) {
    u32 s = lb + p;
    if (s < cap) {
      u64 e = st[p];
      cand[s] = e;
      atomicAdd(&hist2[(u32)(e >> 52)], 1u);
    }
  }
}

// ---------------- Exact 31-bit select over candidates (single block) ----------
// Level 0 comes free from hist2 (built in k_main). One full candidate scan does
// level-1 histogram AND compacts boundary-bin entries to candB; levels 2 + tie
// then only touch the compacted subset.
__global__ void __launch_bounds__(1024) k_refine(u32* __restrict__ ctrl,
                                                 const u64* __restrict__ cand,
                                                 u32 cap, u32 K,
                                                 const u32* __restrict__ hist2,
                                                 u64* __restrict__ candB) {
  __shared__ u32 h[2048], h2[2048];
  __shared__ u32 res[8];
  __shared__ u32 tie[2048];
  __shared__ u32 nt, nb;
  u32 t = threadIdx.x;
  u32 lane = t & 63u;
  u32 nc = ctrl[C_NC]; if (nc > cap) nc = cap;

  // level 0: suffix-sum of precomputed exact coarse histogram
  h[t] = hist2[t]; h[t + 1024] = hist2[t + 1024];
  if (t == 0) { nt = 0; nb = 0; }
  __syncthreads();
  u32* src = h; u32* dst = h2;
  for (u32 off = 1; off < 2048; off <<= 1) {
    for (u32 i = t; i < 2048; i += 1024) {
      u32 v = src[i];
      if (i + off < 2048) v += src[i + off];
      dst[i] = v;
    }
    __syncthreads();
    u32* tmp = src; src = dst; dst = tmp;
  }
  for (u32 i = t; i < 2048; i += 1024) {
    u32 cum = src[i];
    u32 nxt = (i + 1 < 2048) ? src[i + 1] : 0u;
    if (cum >= K && nxt < K) { res[0] = i; res[1] = nxt; }
  }
  __syncthreads();
  u32 B0 = res[0];
  u32 r0 = K - res[1];
  __syncthreads();

  // level 1: single full scan — hist of bits 19..10 for bin==B0, plus compaction
  h[t] = 0;
  __syncthreads();
  for (u32 i = t; i < nc; i += 1024) {
    u64 e = cand[i];
    u32 u = (u32)(e >> 32);
    bool pred = ((u >> 20) == B0);
    if (pred) atomicAdd(&h[(u >> 10) & 1023u], 1u);
    // wave-aggregated compaction append
    u64 mask = __ballot(pred);
    if (mask) {
      u32 pre = (u32)__popcll(mask & ((1ull << lane) - 1ull));
      u32 cntw = (u32)__popcll(mask);
      u32 leader = (u32)__ffsll((unsigned long long)mask) - 1u;
      u32 base = 0;
      if (lane == leader) base = atomicAdd(&nb, cntw);
      base = (u32)__shfl((int)base, (int)leader, 64);
      if (pred) candB[base + pre] = e;
    }
  }
  __syncthreads();
  u32 cntB = nb;
  src = h; dst = h2;
  for (u32 off = 1; off < 1024; off <<= 1) {
    u32 v = src[t];
    if (t + off < 1024) v += src[t + off];
    dst[t] = v;
    __syncthreads();
    u32* tmp = src; src = dst; dst = tmp;
  }
  {
    u32 cum = src[t];
    u32 nxt = (t + 1 < 1024) ? src[t + 1] : 0u;
    if (cum >= r0 && nxt < r0) { res[2] = t; res[3] = nxt; }
  }
  __syncthreads();
  u32 B1 = res[2];
  u32 r1 = r0 - res[3];
  u32 hi21 = (B0 << 10) | B1;
  __syncthreads();

  // level 2: bits 9..0, scanning only the compacted boundary-bin subset
  h[t] = 0;
  __syncthreads();
  for (u32 i = t; i < cntB; i += 1024) {
    u32 u = (u32)(candB[i] >> 32);
    if ((u >> 10) == hi21) atomicAdd(&h[u & 1023u], 1u);
  }
  __syncthreads();
  src = h; dst = h2;
  for (u32 off = 1; off < 1024; off <<= 1) {
    u32 v = src[t];
    if (t + off < 1024) v += src[t + off];
    dst[t] = v;
    __syncthreads();
    u32* tmp = src; src = dst; dst = tmp;
  }
  {
    u32 cum = src[t];
    u32 nxt = (t + 1 < 1024) ? src[t + 1] : 0u;
    if (cum >= r1 && nxt < r1) { res[4] = t; res[5] = nxt; }
  }
  __syncthreads();
  u32 B2 = res[4];
  u32 r2 = r1 - res[5];
  u32 T = (hi21 << 10) | B2;
  __syncthreads();

  // tie resolution over compacted subset: r2-th smallest index among u == T
  for (u32 i = t; i < cntB; i += 1024) {
    u64 e = candB[i];
    if ((u32)(e >> 32) == T) {
      u32 p = atomicAdd(&nt, 1u);
      if (p < 2048u) tie[p] = (u32)e & 0x7fffffffu;
    }
  }
  __syncthreads();
  u32 ntc = nt; if (ntc > 2048u) ntc = 2048u;
  for (u32 i = t; i < ntc; i += 1024) {
    u32 ti = tie[i];
    u32 rank = 0;
    for (u32 j = 0; j < ntc; j++) rank += (tie[j] < ti) ? 1u : 0u;
    if (rank == r2 - 1u) ctrl[C_CUT] = ti;
  }
  if (t == 0) ctrl[C_T] = T;
}

// ---------------- Patch chosen candidates (block-aggregated member append) --------
__global__ void __launch_bounds__(256) k_patch(u32* __restrict__ ctrl,
                                               const u64* __restrict__ cand, u32 cap,
                                               float* __restrict__ res_out,
                                               float* __restrict__ sp_out,
                                               u64* __restrict__ memb) {
  __shared__ u64 st[PATCH_CHUNK];
  __shared__ u32 cnt, basep;
  u32 b0 = blockIdx.x * PATCH_CHUNK;
  u32 nc = ctrl[C_NC]; if (nc > cap) nc = cap;
  if (b0 >= nc) return;                    // uniform early-out, before any sync
  if (threadIdx.x == 0) cnt = 0;
  __syncthreads();
  u32 T = ctrl[C_T];
  u32 cut = ctrl[C_CUT];
  for (u32 j = threadIdx.x; j < PATCH_CHUNK; j += 256u) {
    u32 i = b0 + j;
    if (i < nc) {
      u64 e = cand[i];
      u32 u = (u32)(e >> 32);
      u32 low = (u32)e;
      u32 idx = low & 0x7fffffffu;
      bool chosen = (u > T) || (u == T && idx <= cut);
      if (chosen) {
        u32 cb = u | (low & 0x80000000u);
        res_out[idx] = 0.f;
        sp_out[idx] = __uint_as_float(cb);
        u32 p = atomicAdd(&cnt, 1u);
        st[p] = ((u64)fkey32(cb) << 32) | (u64)idx;
      }
    }
  }
  __syncthreads();
  if (threadIdx.x == 0) basep = atomicAdd(&ctrl[C_NM], cnt);
  __syncthreads();
  u32 bp = basep;
  for (u32 p = threadIdx.x; p < cnt; p += 256u)
    memb[bp + p] = st[p];
}

// ---------------- Rank pass: partial[ct][m] = #{j in chunk ct : key_j < key_m} -----
__global__ void __launch_bounds__(256) k_rank(const u64* __restrict__ memb,
                                              u32* __restrict__ partial,
                                              int k, int mpad) {
  __shared__ u64 s[RCHUNK];
  u32 cbase = blockIdx.y * RCHUNK;
  for (u32 j = threadIdx.x; j < RCHUNK; j += 256u) {
    u32 jj = cbase + j;
    s[j] = (jj < (u32)k) ? memb[jj] : ~0ull;
  }
  __syncthreads();
  u32 m0 = blockIdx.x * 1024u + threadIdx.x * 4u;
  u64 k0 = (m0 + 0 < (u32)k) ? memb[m0 + 0] : 0ull;
  u64 k1 = (m0 + 1 < (u32)k) ? memb[m0 + 1] : 0ull;
  u64 k2 = (m0 + 2 < (u32)k) ? memb[m0 + 2] : 0ull;
  u64 k3 = (m0 + 3 < (u32)k) ? memb[m0 + 3] : 0ull;
  u32 r0 = 0, r1 = 0, r2 = 0, r3 = 0;
  const ulonglong2* s2 = (const ulonglong2*)s;
#pragma unroll 4
  for (int j = 0; j < RCHUNK / 2; j++) {
    ulonglong2 kk = s2[j];
    r0 += (kk.x < k0) + (kk.y < k0);
    r1 += (kk.x < k1) + (kk.y < k1);
    r2 += (kk.x < k2) + (kk.y < k2);
    r3 += (kk.x < k3) + (kk.y < k3);
  }
  u32* row = partial + (size_t)blockIdx.y * (u32)mpad;
  if (m0 + 3 < (u32)k) {
    uint4 v; v.x = r0; v.y = r1; v.z = r2; v.w = r3;
    *(uint4*)(row + m0) = v;
  } else {
    if (m0 + 0 < (u32)k) row[m0 + 0] = r0;
    if (m0 + 1 < (u32)k) row[m0 + 1] = r1;
    if (m0 + 2 < (u32)k) row[m0 + 2] = r2;
    if (m0 + 3 < (u32)k) row[m0 + 3] = r3;
  }
}

// ---------------- Reduce partial ranks + emit outputs ----------
__global__ void __launch_bounds__(256) k_out(const u64* __restrict__ memb,
                                             const u32* __restrict__ partial,
                                             float* __restrict__ out,
                                             int k, int mpad, int ct) {
  int m = blockIdx.x * 256 + (int)threadIdx.x;
  if (m >= k) return;
  u32 rank = 0;
  for (int c = 0; c < ct; c++)
    rank += partial[(size_t)c * (u32)mpad + (u32)m];
  u64 e = memb[m];
  u32 idx = (u32)e & 0x7fffffffu;
  u32 h = (u32)(e >> 32);
  u32 fb = (h & 0x80000000u) ? (h ^ 0x80000000u) : ~h;
  out[rank] = (float)idx;
  out[k + rank] = __uint_as_float(fb);
}

extern "C" void kernel_launch(void* const* d_in, const int* in_sizes, int n_in,
                              void* d_out, int out_size, void* d_ws, size_t ws_size,
                              hipStream_t stream) {
  const float* g   = (const float*)d_in[0];
  const float* r   = (const float*)d_in[1];
  const float* mom = (const float*)d_in[2];
  int n = in_sizes[0];
  int k = (out_size - 2 * n) / 2;
  int n4 = n / 4;

  float* out = (float*)d_out;
  float* res_out = out + 2 * (size_t)k;
  float* sp_out  = res_out + (size_t)n;

  unsigned char* ws = (unsigned char*)d_ws;
  u32* ctrl    = (u32*)ws;                    // [0, 256)
  u32* shist   = (u32*)(ws + 1024);           // [1024, 9216)
  u32* hist2   = (u32*)(ws + 9216);           // [9216, 17408) exact coarse hist
  u64* memb    = (u64*)(ws + 32768);          // ~1 MB member list
  u32* partial = (u32*)(ws + 1048576);        // up to 8 MB partial ranks
  u64* candB   = (u64*)(ws + 1048576);        // aliases partial (dead until k_rank)
  size_t cand_off = 9437184;                  // 9 MB
  u64* cand    = (u64*)(ws + cand_off);

  u32 cap = 524288u;
  if (ws_size < cand_off + (size_t)cap * 8)
    cap = (u32)((ws_size - cand_off) / 8);

  // sample target: expected full-data candidate count ~ 3*k (clamped)
  int nsc = n4 / 32768; if (nsc < 1) nsc = 1;
  double sampleN = (double)nsc * 1024.0 * 4.0;
  double want = 3.0 * (double)k;
  double capd = 0.5 * (double)cap;
  if (want > capd) want = capd;
  if (want < 1.5 * (double)k) want = 1.5 * (double)k;
  u32 target = (u32)(want * sampleN / (double)n) + 1u;

  int mtiles = (k + 1023) / 1024;
  int mpad   = mtiles * 1024;
  int ct     = (k + RCHUNK - 1) / RCHUNK;

  hipMemsetAsync(ws, 0, 32768, stream);                          // ctrl + shist + hist2

  k_sample<<<nsc, 256, 0, stream>>>((const float4*)g, (const float4*)r, shist, n4);
  k_pick<<<1, 1024, 0, stream>>>(shist, ctrl, target);
  k_main<<<(n4 + (int)MAIN_ELEMS - 1) / (int)MAIN_ELEMS, 256, 0, stream>>>(
      (const f4*)g, (const f4*)r, mom, (f4*)res_out, (f4*)sp_out, ctrl, cand, cap, n4, hist2);
  k_refine<<<1, 1024, 0, stream>>>(ctrl, cand, cap, (u32)k, hist2, candB);
  k_patch<<<(int)((cap + PATCH_CHUNK - 1) / PATCH_CHUNK), 256, 0, stream>>>(
      ctrl, cand, cap, res_out, sp_out, memb);

  dim3 rg((u32)mtiles, (u32)ct);
  k_rank<<<rg, 256, 0, stream>>>(memb, partial, k, mpad);
  k_out<<<(k + 255) / 256, 256, 0, stream>>>(memb, partial, out, k, mpad, ct);
}